// Round 2
// baseline (739.029 us; speedup 1.0000x reference)
//
#include <hip/hip_runtime.h>
#include <math.h>

#define BATCH 4096
#define NODES 256
#define FDIM  128
#define HID   16
#define CH    64            // rows per staged chunk
#define NCH   (NODES / CH)  // 4 chunks

// global -> LDS direct copy, 16B per lane. LDS dest is wave-uniform base +
// lane*16 (HW rule); global source is per-lane (we pre-swizzle it there).
__device__ __forceinline__ void gload_lds16(const float* g, void* l) {
    __builtin_amdgcn_global_load_lds(
        (const __attribute__((address_space(1))) void*)g,
        (__attribute__((address_space(3))) void*)l, 16, 0, 0);
}

// One block per batch element b. 256 threads = 4 waves.
// Wave w owns h-columns 4w..4w+3; lane owns row (node) within chunk.
// x chunk staged coalesced via global_load_lds with XOR-swizzled source so
// ds_read_b128 at stride-512B across lanes hits all 32 banks (rule #21:
// linear LDS dest + inverse-swizzled source + swizzled read).
__launch_bounds__(256, 2)
__global__ void mta_kernel(const float* __restrict__ x,
                           const float* __restrict__ a1,
                           const float* __restrict__ a2,
                           const float* __restrict__ adj,
                           const int*  __restrict__ node_index,
                           const int*  __restrict__ type_index,
                           float* __restrict__ out) {
    const int b    = blockIdx.x;
    const int tid  = threadIdx.x;
    const int lane = tid & 63;
    const int w    = tid >> 6;

    __shared__ float4 xbuf[2][CH][FDIM / 4];  // 2 x 32KB
    __shared__ float  ep[4][NODES];           // per-wave e partials (4KB)
    __shared__ float  part[16][17];           // c0 partials
    __shared__ float  c0s[HID];
    __shared__ float  redm[4];
    __shared__ float  reds[4];

    const int t  = __builtin_amdgcn_readfirstlane(type_index[b]);
    const int ni = __builtin_amdgcn_readfirstlane(node_index[0]);

    const float* At  = a1 + (size_t)t * (2 * FDIM * HID); // top    [FDIM][HID]
    const float* Ab  = At + FDIM * HID;                   // bottom [FDIM][HID]
    const float* a2t = a2 + t * HID;
    const float* xb  = x + (size_t)b * NODES * FDIM;

    // stage chunk c into xbuf[bsel]: wave w, inst i covers LDS float4-slots
    // q = (w*8+i)*64 + lane  ->  row rr = q>>5, slot ss = q&31.
    // content: xbuf[rr][ss] = X[c*64+rr][ss ^ (rr&7)]
    auto stage = [&](int bsel, int c) {
        #pragma unroll
        for (int i = 0; i < 8; ++i) {
            const int q  = (w * 8 + i) * 64 + lane;
            const int rr = q >> 5;
            const int sg = (q & 31) ^ (rr & 7);
            gload_lds16(xb + (size_t)(c * CH + rr) * FDIM + sg * 4,
                        (char*)(&xbuf[bsel][0][0]) + (size_t)(w * 8 + i) * 1024);
        }
    };

    // ---- issue stage of chunk 0 first so HBM loads fly under the c0 phase ----
    stage(0, 0);

    // ---- c0[h] = sum_f x[b,ni,f] * At[f][h] (tiny, cooperative) ----
    {
        const float* x0 = xb + (size_t)ni * FDIM;
        const int f2 = tid >> 4;   // 16 f-groups of 8
        const int h  = tid & 15;
        float p = 0.f;
        #pragma unroll
        for (int j = 0; j < 8; ++j) {
            const int f = f2 * 8 + j;
            p = fmaf(x0[f], At[f * HID + h], p);
        }
        part[f2][h] = p;
    }
    __syncthreads();
    if (tid < 16) {
        float s = 0.f;
        #pragma unroll
        for (int g = 0; g < 16; ++g) s += part[g][tid];
        c0s[tid] = s;
    }
    __syncthreads();   // c0s ready; own vmcnt drained => xbuf[0] complete for all

    const int hbase = w * 4;

    // ---- main loop: 4 chunks, double-buffered ----
    #pragma unroll
    for (int c = 0; c < NCH; ++c) {
        if (c + 1 < NCH) stage((c & 1) ^ 1, c + 1);   // prefetch next chunk

        const float4* xr = &xbuf[c & 1][lane][0];
        float acc[4];
        #pragma unroll
        for (int h = 0; h < 4; ++h) acc[h] = 0.f;

        #pragma unroll
        for (int j = 0; j < 32; ++j) {
            const float4 xv = xr[j ^ (lane & 7)];     // swizzled read
            const float* Wf = Ab + (j * 4) * HID + hbase;  // uniform -> s_load
            #pragma unroll
            for (int k = 0; k < 4; ++k) {
                const float xk = (k == 0) ? xv.x : (k == 1) ? xv.y
                               : (k == 2) ? xv.z : xv.w;
                #pragma unroll
                for (int h = 0; h < 4; ++h)
                    acc[h] = fmaf(xk, Wf[k * HID + h], acc[h]);
            }
        }

        // partial e over this wave's h-quad (inner lrelu per h, sum is linear)
        float epart = 0.f;
        #pragma unroll
        for (int h = 0; h < 4; ++h) {
            float v = acc[h] + c0s[hbase + h];
            v = (v > 0.f) ? v : 0.01f * v;
            epart = fmaf(v, a2t[hbase + h], epart);
        }
        ep[w][c * CH + lane] = epart;

        __syncthreads();  // buffer (c&1)^1 staged + all waves done reading (c&1)
    }

    // ---- combine h-quads, outer lrelu ----
    float e = ep[0][tid] + ep[1][tid] + ep[2][tid] + ep[3][tid];
    e = (e > 0.f) ? e : 0.01f * e;

    // ---- masked softmax over 256 nodes ----
    const float m   = adj[tid];
    float       val = (m > 0.f) ? e : -INFINITY;

    float mx = val;
    #pragma unroll
    for (int off = 32; off; off >>= 1) mx = fmaxf(mx, __shfl_xor(mx, off));
    const int wid = tid >> 6;
    if ((tid & 63) == 0) redm[wid] = mx;
    __syncthreads();
    mx = fmaxf(fmaxf(redm[0], redm[1]), fmaxf(redm[2], redm[3]));

    float p = (m > 0.f) ? __expf(e - mx) : 0.f;
    float s = p;
    #pragma unroll
    for (int off = 32; off; off >>= 1) s += __shfl_xor(s, off);
    if ((tid & 63) == 0) reds[wid] = s;
    __syncthreads();
    const float Z = reds[0] + reds[1] + reds[2] + reds[3];

    out[(size_t)b * NODES + tid] = p / Z;
}

extern "C" void kernel_launch(void* const* d_in, const int* in_sizes, int n_in,
                              void* d_out, int out_size, void* d_ws, size_t ws_size,
                              hipStream_t stream) {
    const float* x   = (const float*)d_in[0];
    const float* a1  = (const float*)d_in[1];
    const float* a2  = (const float*)d_in[2];
    const float* adj = (const float*)d_in[3];
    const int*   ni  = (const int*)d_in[4];
    const int*   ti  = (const int*)d_in[5];
    float* out = (float*)d_out;

    mta_kernel<<<BATCH, NODES, 0, stream>>>(x, a1, a2, adj, ni, ti, out);
}